// Round 2
// baseline (906.759 us; speedup 1.0000x reference)
//
#include <hip/hip_runtime.h>

#define NN    20000   // nodes
#define NRELH 16      // original relations
#define RTOT  33      // 2*16+1
#define NHID  64
#define NCLS  16

// ---- count (rel,dst) and (rel,src) over original edges ----
__global__ __launch_bounds__(256) void count_kernel(
    const int* __restrict__ src, const int* __restrict__ rel,
    const int* __restrict__ dst, int E,
    int* __restrict__ cntA, int* __restrict__ cntB) {
    int e = blockIdx.x * blockDim.x + threadIdx.x;
    if (e >= E) return;
    int r = rel[e];
    atomicAdd(&cntA[r * NN + dst[e]], 1);
    atomicAdd(&cntB[r * NN + src[e]], 1);
}

// ---- layer 1: h[s,:] += val * w1[rowsel(e), :], one wave (64 lanes) per edge ----
__global__ __launch_bounds__(256) void layer1_kernel(
    const int* __restrict__ src, const int* __restrict__ rel,
    const int* __restrict__ dst, int E,
    const float* __restrict__ w1,
    const int* __restrict__ cntA, const int* __restrict__ cntB,
    float* __restrict__ h) {
    int gid = blockIdx.x * blockDim.x + threadIdx.x;
    int e    = gid >> 6;   // edge index in augmented list
    int lane = gid & 63;   // hidden index
    int EA = 2 * E + NN;
    if (e >= EA) return;
    int s, row; float val;
    if (e < E) {                       // original: s=src, o=dst, r=rel
        int r = rel[e]; s = src[e]; int d = dst[e];
        row = r * NN + d;
        val = 1.0f / (float)cntB[r * NN + s];     // swapped norm (inverse block count)
    } else if (e < 2 * E) {            // inverse: s=dst, o=src, r=rel+16
        int e0 = e - E;
        int r = rel[e0]; int sr = src[e0]; int d = dst[e0];
        s = d; row = (r + NRELH) * NN + sr;
        val = 1.0f / (float)cntA[r * NN + d];     // swapped norm (original block count)
    } else {                           // self-loop: count is always 1
        int n = e - 2 * E;
        s = n; row = 2 * NRELH * NN + n;
        val = 1.0f;
    }
    float wv = w1[(long long)row * NHID + lane];  // coalesced 256B per wave
    atomicAdd(&h[s * NHID + lane], val * wv);
}

// ---- bias + relu on h ----
__global__ __launch_bounds__(256) void bias_relu_kernel(
    float* __restrict__ h, const float* __restrict__ b1) {
    int i = blockIdx.x * blockDim.x + threadIdx.x;
    if (i >= NN * NHID) return;
    float v = h[i] + b1[i & (NHID - 1)];
    h[i] = v > 0.0f ? v : 0.0f;
}

// ---- out init to b2 (harness poisons d_out) ----
__global__ __launch_bounds__(256) void init_out_kernel(
    float* __restrict__ out, const float* __restrict__ b2) {
    int i = blockIdx.x * blockDim.x + threadIdx.x;
    if (i >= NN * NCLS) return;
    out[i] = b2[i & (NCLS - 1)];
}

// ---- layer 2 fused with einsum: out[s,c] += val * sum_i h[o,i]*w2[r,i,c] ----
// 16 threads per augmented edge; thread = output class c.
__global__ __launch_bounds__(256) void layer2_kernel(
    const int* __restrict__ src, const int* __restrict__ rel,
    const int* __restrict__ dst, int E,
    const float* __restrict__ h, const float* __restrict__ w2,
    const int* __restrict__ cntA, const int* __restrict__ cntB,
    float* __restrict__ out) {
    int gid = blockIdx.x * blockDim.x + threadIdx.x;
    int e = gid >> 4;
    int c = gid & 15;
    int EA = 2 * E + NN;
    if (e >= EA) return;
    int s, o, r; float val;
    if (e < E) {
        r = rel[e]; s = src[e]; o = dst[e];
        val = 1.0f / (float)cntB[r * NN + s];
    } else if (e < 2 * E) {
        int e0 = e - E;
        int r0 = rel[e0]; s = dst[e0]; o = src[e0]; r = r0 + NRELH;
        val = 1.0f / (float)cntA[r0 * NN + s];
    } else {
        int n = e - 2 * E; r = 2 * NRELH; s = n; o = n; val = 1.0f;
    }
    const float* __restrict__ hrow = &h[o * NHID];
    const float* __restrict__ wcol = &w2[(r * NHID) * NCLS + c];
    float acc = 0.0f;
#pragma unroll
    for (int i = 0; i < NHID; ++i) acc += hrow[i] * wcol[i * NCLS];
    atomicAdd(&out[s * NCLS + c], val * acc);
}

extern "C" void kernel_launch(void* const* d_in, const int* in_sizes, int n_in,
                              void* d_out, int out_size, void* d_ws, size_t ws_size,
                              hipStream_t stream) {
    const int*   src = (const int*)d_in[0];
    const int*   rel = (const int*)d_in[1];
    const int*   dst = (const int*)d_in[2];
    const float* w1  = (const float*)d_in[3];
    const float* b1  = (const float*)d_in[4];
    const float* w2  = (const float*)d_in[5];
    const float* b2  = (const float*)d_in[6];
    float* out = (float*)d_out;
    const int E = in_sizes[0];

    // workspace layout: cntA[16*NN] | cntB[16*NN] | h[NN*NHID]   (7.68 MB)
    int*   cntA = (int*)d_ws;
    int*   cntB = cntA + NRELH * NN;
    float* h    = (float*)(cntB + NRELH * NN);
    size_t zbytes = (size_t)(2 * NRELH * NN) * 4 + (size_t)NN * NHID * 4;
    hipMemsetAsync(d_ws, 0, zbytes, stream);

    const int EA = 2 * E + NN;

    count_kernel<<<(E + 255) / 256, 256, 0, stream>>>(src, rel, dst, E, cntA, cntB);

    {
        long long tot = (long long)EA * 64;
        int blocks = (int)((tot + 255) / 256);
        layer1_kernel<<<blocks, 256, 0, stream>>>(src, rel, dst, E, w1, cntA, cntB, h);
    }

    bias_relu_kernel<<<(NN * NHID + 255) / 256, 256, 0, stream>>>(h, b1);
    init_out_kernel<<<(NN * NCLS + 255) / 256, 256, 0, stream>>>(out, b2);

    {
        long long tot = (long long)EA * 16;
        int blocks = (int)((tot + 255) / 256);
        layer2_kernel<<<blocks, 256, 0, stream>>>(src, rel, dst, E, h, w2, cntA, cntB, out);
    }
}